// Round 15
// baseline (332.122 us; speedup 1.0000x reference)
//
#include <hip/hip_runtime.h>
#include <math.h>

// GSS block on MI355X. Shapes: B=2, L=4096, DIM=1024, HID=4096, H=DSSH=512, N=DSSN=512.
// R15 (= R14 bugfix): ring-buffer GEMM offsets corrected for BK=32 —
// buffer stride 16384 B (stage) / 8192 u16 (read), B half at +8192 B / +4096 u16.
// R14 had BK=64-sized offsets -> LDS OOB -> absmax 4.3. Pipeline logic unchanged:
// 4-deep ring, stage kt+3, counted vmcnt(12/8/4/0), never drain mid-loop.

typedef unsigned short u16;
typedef unsigned int u32;
typedef __attribute__((ext_vector_type(8))) __bf16 bf16x8;
typedef __attribute__((ext_vector_type(4))) float f32x4;
typedef __attribute__((ext_vector_type(4))) u32 u32x4;

__device__ __forceinline__ u16 f2bf(float f) {
  u32 u = __float_as_uint(f);
  u32 r = u + 0x7FFFu + ((u >> 16) & 1u);
  return (u16)(r >> 16);
}
__device__ __forceinline__ float bf2f(u16 h) { return __uint_as_float(((u32)h) << 16); }

// ================================================================ device bodies
__device__ __forceinline__ void trans_conv_body(
    int bid, const float* __restrict__ in, u16* __restrict__ out, int K, int N,
    float (*t)[33]) {
  int tx = threadIdx.x & 31, ty = threadIdx.x >> 5;
  int nb = N >> 5;
  int k0 = (bid / nb) << 5;
  int n0 = (bid % nb) << 5;
#pragma unroll
  for (int i = 0; i < 32; i += 8)
    t[ty + i][tx] = in[(size_t)(k0 + ty + i) * N + n0 + tx];
  __syncthreads();
#pragma unroll
  for (int i = 0; i < 32; i += 8)
    out[(size_t)(n0 + ty + i) * K + k0 + tx] = f2bf(t[tx][ty + i]);
}

__device__ __forceinline__ void ln1_body(
    int bid, const float* __restrict__ in, const float* __restrict__ gw,
    const float* __restrict__ gb, u16* __restrict__ outp, float* sbuf) {
  const int D = 1024;
  int tid = threadIdx.x;
  const float4* r4 = (const float4*)(in + (size_t)bid * D);
  float4 v = r4[tid];
  float s = v.x + v.y + v.z + v.w;
  float ss = fmaf(v.x, v.x, fmaf(v.y, v.y, fmaf(v.z, v.z, v.w * v.w)));
#pragma unroll
  for (int o = 32; o >= 1; o >>= 1) { s += __shfl_xor(s, o); ss += __shfl_xor(ss, o); }
  float* sa = sbuf;
  float* sb = sbuf + 8;
  if ((tid & 63) == 0) { sa[tid >> 6] = s; sb[tid >> 6] = ss; }
  __syncthreads();
  float S = sa[0] + sa[1] + sa[2] + sa[3];
  float SS = sb[0] + sb[1] + sb[2] + sb[3];
  float mean = S / (float)D;
  float var = SS / (float)D - mean * mean;
  float inv = rsqrtf(var + 1e-5f);
  float4 wv = ((const float4*)gw)[tid];
  float4 bv = ((const float4*)gb)[tid];
  ushort4 o;
  o.x = f2bf((v.x - mean) * inv * wv.x + bv.x);
  o.y = f2bf((v.y - mean) * inv * wv.y + bv.y);
  o.z = f2bf((v.z - mean) * inv * wv.z + bv.z);
  o.w = f2bf((v.w - mean) * inv * wv.w + bv.w);
  ((ushort4*)outp)[(size_t)bid * (D >> 2) + tid] = o;
}

__device__ __forceinline__ void kgen_c_body(
    int bid, const float* __restrict__ LR, const float* __restrict__ LI,
    const float* __restrict__ CR, const float* __restrict__ CI, u16* __restrict__ Ct) {
  int idx0 = bid * 256 + threadIdx.x;
  int h = idx0 >> 9, n = idx0 & 511;
  float eLR = expf(LR[n]), eLI = expf(LI[n]);
  float lre = -eLR, lim = eLI;
  float er = expf(lre);
  float c, s;
  sincosf(lim, &s, &c);
  float wr = er * c - 1.0f, wi = er * s;
  float den = lre * lre + lim * lim;
  float gr = (wr * lre + wi * lim) / den;
  float gi = (wi * lre - wr * lim) / den;
  float cr = CR[(size_t)h * 512 + n], ci = CI[(size_t)h * 512 + n];
  float ccr = cr * gr - ci * gi;
  float cci = cr * gi + ci * gr;
  Ct[(size_t)h * 1024 + n] = f2bf(ccr);
  Ct[(size_t)h * 1024 + 512 + n] = f2bf(-cci);
}

__device__ __forceinline__ void twfill_body(int bid, float4* __restrict__ twg4) {
  int j = bid * 256 + threadIdx.x;
  float t1 = -6.2831853071795864769f * (float)j / 8192.0f;
  float s1, c1, s2, c2;
  sincosf(t1, &s1, &c1);
  sincosf(2.0f * t1, &s2, &c2);
  twg4[j] = {c1, s1, c2, s2};
}

__device__ __forceinline__ void tab_body(
    int bid, const float* __restrict__ LR, const float* __restrict__ LI,
    double* __restrict__ aexp, double* __restrict__ fexp) {
  int n = bid * 256 + threadIdx.x;
  if (n < 512) {
    aexp[n] = exp((double)LR[n]);
    fexp[n] = exp((double)LI[n]) * 0.15915494309189533577;
  }
}

__device__ __forceinline__ void ln_stats_body(
    int bid, const u16* __restrict__ xdTb, float* __restrict__ meanv,
    float* __restrict__ invv, float* sbuf) {
  int lane = threadIdx.x & 63;
  int seg = threadIdx.x >> 6;
  int col = bid * 64 + lane;
  float s = 0.f, ss = 0.f;
  const u16* p = xdTb + (size_t)(seg * 128) * 8192 + col;
#pragma unroll 8
  for (int r = 0; r < 128; ++r) {
    float v = bf2f(p[(size_t)r * 8192]);
    s += v; ss = fmaf(v, v, ss);
  }
  float* sa = sbuf;
  float* sb = sbuf + 256;
  sa[seg * 64 + lane] = s; sb[seg * 64 + lane] = ss;
  __syncthreads();
  if (threadIdx.x < 64) {
    float S = sa[lane] + sa[64 + lane] + sa[128 + lane] + sa[192 + lane];
    float SS = sb[lane] + sb[64 + lane] + sb[128 + lane] + sb[192 + lane];
    float mean = S * (1.0f / 512.0f);
    float var = SS * (1.0f / 512.0f) - mean * mean;
    meanv[bid * 64 + lane] = mean;
    invv[bid * 64 + lane] = rsqrtf(var + 1e-5f);
  }
}

// ---------------------------------------------------------------- ring-buffer GEMM
// 128x128 tile, BK=32, 4 waves (2x2), 4 LDS buffers of 16384 B each (64 KiB,
// 2 blocks/CU). Per tile: stage kt+3, counted vmcnt(12/8/4/0), 2 barriers,
// 8 ds_read_b128 + 16 MFMA. Swizzle: phys_slot = kq ^ (row&3), source
// pre-swizzled. Buffer layout (bytes): [A 8192 | B 8192] per ring slot.

#define RING_STAGE(AP, BP, K, kt)                                                         \
  {                                                                                       \
    const u32 cb = (u32)((kt) & 3) * 16384u;                                              \
    const size_t kof = (size_t)(kt) << 5;                                                 \
    _Pragma("unroll") for (int i = 0; i < 2; ++i) {                                       \
      u32 da = cb + (u32)(i * 64 + wv16) * 64u;                                           \
      __builtin_amdgcn_global_load_lds(                                                   \
          (const __attribute__((address_space(1))) void*)((AP) + (size_t)(i * 64) * (K) + kof), \
          (__attribute__((address_space(3))) void*)(ldsc + da), 16, 0, 0);                \
      __builtin_amdgcn_global_load_lds(                                                   \
          (const __attribute__((address_space(1))) void*)((BP) + (size_t)(i * 64) * (K) + kof), \
          (__attribute__((address_space(3))) void*)(ldsc + da + 8192), 16, 0, 0);         \
    }                                                                                     \
  }

#define RING_LOOP(Aptr, Bptr, K, ACC)                                                     \
  {                                                                                       \
    const int NT = (K) >> 5;                                                              \
    RING_STAGE(Aptr, Bptr, K, 0);                                                         \
    RING_STAGE(Aptr, Bptr, K, 1);                                                         \
    RING_STAGE(Aptr, Bptr, K, 2);                                                         \
    asm volatile("s_waitcnt vmcnt(8)" ::: "memory");                                      \
    __builtin_amdgcn_s_barrier();                                                         \
    for (int kt = 0; kt < NT; ++kt) {                                                     \
      if (kt + 3 < NT) RING_STAGE(Aptr, Bptr, K, kt + 3);                                 \
      if (kt + 3 < NT)      asm volatile("s_waitcnt vmcnt(12)" ::: "memory");             \
      else if (kt + 2 < NT) asm volatile("s_waitcnt vmcnt(8)" ::: "memory");              \
      else if (kt + 1 < NT) asm volatile("s_waitcnt vmcnt(4)" ::: "memory");              \
      else                  asm volatile("s_waitcnt vmcnt(0)" ::: "memory");              \
      __builtin_amdgcn_s_barrier();                                                       \
      const u32 ab = (u32)(kt & 3) * 8192u;                                               \
      bf16x8 af[4], bv[4];                                                                \
      _Pragma("unroll") for (int mi = 0; mi < 4; ++mi) {                                  \
        int ra = wm * 64 + mi * 16 + lr;                                                  \
        af[mi] = *(const bf16x8*)&lds[ab + ra * 32 + slp];                                \
      }                                                                                   \
      _Pragma("unroll") for (int ni = 0; ni < 4; ++ni) {                                  \
        int rb = wn * 64 + ni * 16 + lr;                                                  \
        bv[ni] = *(const bf16x8*)&lds[ab + 4096 + rb * 32 + slp];                         \
      }                                                                                   \
      __builtin_amdgcn_s_setprio(1);                                                      \
      _Pragma("unroll") for (int mi = 0; mi < 4; ++mi)                                    \
        _Pragma("unroll") for (int ni = 0; ni < 4; ++ni)                                  \
          ACC[mi][ni] = __builtin_amdgcn_mfma_f32_16x16x32_bf16(af[mi], bv[ni], ACC[mi][ni], 0, 0, 0); \
      __builtin_amdgcn_s_setprio(0);                                                      \
      __builtin_amdgcn_s_barrier();                                                      \
    }                                                                                     \
  }

// MODE 1: bf16 out   3: f32 C+bias[n]+res[m,n]
template <int MODE>
__device__ __forceinline__ void gemm128s_body(
    int bid0, int nwg, const u16* __restrict__ A, const u16* __restrict__ Bt,
    int M, int N, int K, float* Cf, u16* Cb,
    const float* __restrict__ bias, const float* __restrict__ res, u16* lds) {
  const int tid = threadIdx.x;
  const int lane = tid & 63;
  const int w = tid >> 6;
  const int cpx = nwg >> 3;
  const int bid = (nwg & 7) ? bid0 : (bid0 & 7) * cpx + (bid0 >> 3);
  const int tiles_n = N >> 7;
  const int tm = (bid / tiles_n) << 7;
  const int tn = (bid % tiles_n) << 7;

  const int wm = w >> 1, wn = w & 1;
  const int lr = lane & 15;
  const int kq = lane >> 4;
  const int slp = ((kq ^ (lr & 3)) << 3);
  const int wv16 = w * 16;
  const int srow = wv16 + (lane >> 2);
  const int sslot = (lane & 3) ^ ((lane >> 2) & 3);
  const u16* gA = A + (size_t)(tm + srow) * K + sslot * 8;
  const u16* gB = Bt + (size_t)(tn + srow) * K + sslot * 8;
  auto ldsc = (__attribute__((address_space(3))) char*)lds;

  f32x4 acc[4][4] = {};
  RING_LOOP(gA, gB, K, acc);

  // ---- LDS-shuffle epilogue
  float* lf = (float*)lds + w * (16 * 68);
  const int er = lane >> 2;
  const int ec = (lane & 3) << 4;
  const int gcol = tn + wn * 64 + ec;
#pragma unroll
  for (int mi = 0; mi < 4; ++mi) {
#pragma unroll
    for (int ni = 0; ni < 4; ++ni)
#pragma unroll
      for (int j = 0; j < 4; ++j)
        lf[(kq * 4 + j) * 68 + ni * 16 + lr] = acc[mi][ni][j];
    float v[16];
#pragma unroll
    for (int q = 0; q < 4; ++q)
      *(f32x4*)&v[q * 4] = *(const f32x4*)&lf[er * 68 + ec + q * 4];
    const int gr = tm + wm * 64 + mi * 16 + er;
    if (MODE == 3) {
      const float* rr = res + (size_t)gr * N + gcol;
      const float* br = bias + gcol;
      float* orr = Cf + (size_t)gr * N + gcol;
#pragma unroll
      for (int q = 0; q < 4; ++q) {
        f32x4 rv = *(const f32x4*)(rr + q * 4);
        f32x4 bv4 = *(const f32x4*)(br + q * 4);
        f32x4 ov;
        ov[0] = v[q * 4 + 0] + bv4[0] + rv[0];
        ov[1] = v[q * 4 + 1] + bv4[1] + rv[1];
        ov[2] = v[q * 4 + 2] + bv4[2] + rv[2];
        ov[3] = v[q * 4 + 3] + bv4[3] + rv[3];
        *(f32x4*)(orr + q * 4) = ov;
      }
    } else {
      u32 pk[8];
#pragma unroll
      for (int e = 0; e < 8; ++e)
        pk[e] = (u32)f2bf(v[2 * e]) | ((u32)f2bf(v[2 * e + 1]) << 16);
      u16* orr = Cb + (size_t)gr * N + gcol;
      *(u32x4*)orr = u32x4{pk[0], pk[1], pk[2], pk[3]};
      *(u32x4*)(orr + 8) = u32x4{pk[4], pk[5], pk[6], pk[7]};
    }
  }
}

// ================================================================ kernels
__global__ __launch_bounds__(256) void mega1(
    const float* __restrict__ idxf, const float* __restrict__ n1w, const float* __restrict__ n1b,
    const float* __restrict__ Wxg, const float* __restrict__ Wdin,
    const float* __restrict__ Wgate, const float* __restrict__ Wout,
    u16* __restrict__ Wxg_t, u16* __restrict__ Wdin_t,
    u16* __restrict__ Wgate_t, u16* __restrict__ Wout_t,
    u16* __restrict__ xbf, float4* __restrict__ twg4,
    const float* __restrict__ LR, const float* __restrict__ LI,
    const float* __restrict__ CR, const float* __restrict__ CI,
    u16* __restrict__ Ct, double* __restrict__ aexp, double* __restrict__ fexp) {
  __shared__ __align__(16) char smem[4352];
  int b = (int)blockIdx.x;
  if (b < 8192) { ln1_body(b, idxf, n1w, n1b, xbf, (float*)smem); return; }
  b -= 8192;
  if (b < 4096) { trans_conv_body(b, Wxg, Wxg_t, 1024, 4096, (float(*)[33])smem); return; }
  b -= 4096;
  if (b < 4096) { trans_conv_body(b, Wout, Wout_t, 4096, 1024, (float(*)[33])smem); return; }
  b -= 4096;
  if (b < 2048) { trans_conv_body(b, Wgate, Wgate_t, 512, 4096, (float(*)[33])smem); return; }
  b -= 2048;
  if (b < 512) { trans_conv_body(b, Wdin, Wdin_t, 1024, 512, (float(*)[33])smem); return; }
  b -= 512;
  if (b < 1024) { kgen_c_body(b, LR, LI, CR, CI, Ct); return; }
  b -= 1024;
  if (b < 8) { twfill_body(b, twg4); return; }
  b -= 8;
  tab_body(b, LR, LI, aexp, fexp);
}

__global__ __launch_bounds__(256) void kgen_s2(
    const double* __restrict__ aexp, const double* __restrict__ fexp,
    u16* __restrict__ SRSI) {
  int idx0 = (int)blockIdx.x * 256 + threadIdx.x;
  int l = idx0 >> 10;
  int kk = idx0 & 1023;
  int n = kk & 511;
  double fl = fexp[n] * (double)l;
  float rev = (float)(fl - floor(fl));
  float tri = (kk < 512) ? __builtin_amdgcn_cosf(rev) : __builtin_amdgcn_sinf(rev);
  float al = (float)aexp[n] * (float)l;
  SRSI[idx0] = f2bf(expf(-al) * tri);
}

template <int MODE>
__global__ __launch_bounds__(256, 2) void gemm128s(
    const u16* __restrict__ A, const u16* __restrict__ Bt,
    int M, int N, int K,
    float* Cf, u16* Cb,
    const float* __restrict__ bias, const float* __restrict__ res) {
  __shared__ __align__(16) u16 lds[32768];
  gemm128s_body<MODE>((int)blockIdx.x, (int)gridDim.x, A, Bt, M, N, K, Cf, Cb, bias, res, lds);
}

// l3mix: blocks [0,128) -> KT-gemm, [128,256) -> ln_stats.
__global__ __launch_bounds__(256, 2) void l3mix(
    const u16* __restrict__ Ct, const u16* __restrict__ SRSI, u16* __restrict__ KTb,
    const u16* __restrict__ xdTb, float* __restrict__ meanv, float* __restrict__ invv) {
  __shared__ __align__(16) u16 lds[32768];
  int b = (int)blockIdx.x;
  if (b < 128) {
    gemm128s_body<1>(b, 128, Ct, SRSI, 512, 4096, 1024, nullptr, KTb, nullptr, nullptr, lds);
  } else {
    ln_stats_body(b - 128, xdTb, meanv, invv, (float*)lds);
  }
}

__global__ __launch_bounds__(256) void trans_bf(
    const u16* __restrict__ in, u16* __restrict__ out, int R, int C) {
  __shared__ u16 t[32][34];
  int tx = threadIdx.x & 31, ty = threadIdx.x >> 5;
  int nb = C >> 5;
  int r0 = (blockIdx.x / nb) << 5;
  int c0 = (blockIdx.x % nb) << 5;
#pragma unroll
  for (int i = 0; i < 32; i += 8)
    t[ty + i][tx] = in[(size_t)(r0 + ty + i) * C + c0 + tx];
  __syncthreads();
#pragma unroll
  for (int i = 0; i < 32; i += 8)
    out[(size_t)(c0 + ty + i) * R + r0 + tx] = t[tx][ty + i];
}

// fused gate GEMM: e = (A1@B1t^T) * (A2@B2t^T), bf16 out; two ring loops.
__global__ __launch_bounds__(256, 2) void gemm_fuse2(
    const u16* __restrict__ A1, const u16* __restrict__ B1t, int K1,
    const u16* __restrict__ A2, const u16* __restrict__ B2t, int K2,
    int M, int N, u16* __restrict__ Cb) {
  __shared__ __align__(16) u16 lds[32768];
  const int tid = threadIdx.x;
  const int lane = tid & 63;
  const int w = tid >> 6;
  const int nwg = (int)gridDim.x;
  const int cpx = nwg >> 3;
  const int bid = (nwg & 7) ? (int)blockIdx.x
                            : ((int)blockIdx.x & 7) * cpx + ((int)blockIdx.x >> 3);
  const int tiles_n = N >> 7;
  const int tm = (bid / tiles_n) << 7;
  const int tn = (bid % tiles_n) << 7;

  const int wm = w >> 1, wn = w & 1;
  const int lr = lane & 15;
  const int kq = lane >> 4;
  const int slp = ((kq ^ (lr & 3)) << 3);
  const int wv16 = w * 16;
  const int srow = wv16 + (lane >> 2);
  const int sslot = (lane & 3) ^ ((lane >> 2) & 3);
  auto ldsc = (__attribute__((address_space(3))) char*)lds;

  f32x4 acc1[4][4] = {};
  f32x4 acc2[4][4] = {};

  {
    const u16* gA = A1 + (size_t)(tm + srow) * K1 + sslot * 8;
    const u16* gB = B1t + (size_t)(tn + srow) * K1 + sslot * 8;
    RING_LOOP(gA, gB, K1, acc1);
  }
  {
    const u16* gA = A2 + (size_t)(tm + srow) * K2 + sslot * 8;
    const u16* gB = B2t + (size_t)(tn + srow) * K2 + sslot * 8;
    RING_LOOP(gA, gB, K2, acc2);
  }

#pragma unroll
  for (int mi = 0; mi < 4; ++mi)
#pragma unroll
    for (int ni = 0; ni < 4; ++ni)
#pragma unroll
      for (int j = 0; j < 4; ++j)
        acc1[mi][ni][j] *= acc2[mi][ni][j];

  float* lf = (float*)lds + w * (16 * 68);
  const int er = lane >> 2;
  const int ec = (lane & 3) << 4;
  const int gcol = tn + wn * 64 + ec;
#pragma unroll
  for (int mi = 0; mi < 4; ++mi) {
#pragma unroll
    for (int ni = 0; ni < 4; ++ni)
#pragma unroll
      for (int j = 0; j < 4; ++j)
        lf[(kq * 4 + j) * 68 + ni * 16 + lr] = acc1[mi][ni][j];
    float v[16];
#pragma unroll
    for (int q = 0; q < 4; ++q)
      *(f32x4*)&v[q * 4] = *(const f32x4*)&lf[er * 68 + ec + q * 4];
    const int gr = tm + wm * 64 + mi * 16 + er;
    u32 pk[8];
#pragma unroll
    for (int e = 0; e < 8; ++e)
      pk[e] = (u32)f2bf(v[2 * e]) | ((u32)f2bf(v[2 * e + 1]) << 16);
    u16* orr = Cb + (size_t)gr * N + gcol;
    *(u32x4*)orr = u32x4{pk[0], pk[1], pk[2], pk[3]};
    *(u32x4*)(orr + 8) = u32x4{pk[4], pk[5], pk[6], pk[7]};
  }
}

// ---------------------------------------------------------------- FFT machinery
struct C2 { float x, y; };
__device__ __forceinline__ C2 cadd(C2 a, C2 b) { return {a.x + b.x, a.y + b.y}; }
__device__ __forceinline__ C2 csub(C2 a, C2 b) { return {a.x - b.x, a.y - b.y}; }
__device__ __forceinline__ C2 cmul(C2 a, C2 b) {
  return {a.x * b.x - a.y * b.y, a.x * b.y + a.y * b.x};
}
__device__ __forceinline__ C2 cmulni(C2 a) { return {a.y, -a.x}; }

__device__ __forceinline__ int swz(int a) {
  return a ^ ((a >> 7) & 15) ^ ((a >> 11) & 3) ^ ((a >> 2) & 8) ^ ((a >> 3) & 2) ^ ((a >> 4) & 4);
}

#define BR13(x) ((int)(__brev((u32)(x)) >> 19))
#define RS 0.70710678118654752f

__device__ __forceinline__ void dif4(C2& a, C2& b, C2& c, C2& d, float4 wv) {
  C2 w = {wv.x, wv.y}, wm = {wv.y, -wv.x}, w2 = {wv.z, wv.w};
  C2 a1 = cadd(a, c);
  C2 c1 = cmul(csub(a, c), w);
  C2 b1 = cadd(b, d);
  C2 d1 = cmul(csub(b, d), wm);
  a = cadd(a1, b1);
  b = cmul(csub(a1, b1), w2);
  c = cadd(c1, d1);
  d = cmul(csub(c1, d1), w2);
}
__device__ __forceinline__ void dit4(C2& a, C2& b, C2& c, C2& d, float4 wv) {
  C2 w = {wv.x, wv.y}, wm = {wv.y, -wv.x}, wa = {wv.z, wv.w};
  C2 t = cmul(wa, b);
  C2 a1 = cadd(a, t), b1 = csub(a, t);
  C2 u = cmul(wa, d);
  C2 c1 = cadd(c, u), d1 = csub(c, u);
  C2 v = cmul(w, c1);
  C2 xx = cmul(wm, d1);
  a = cadd(a1, v);
  c = csub(a1, v);
  b = cadd(b1, xx);
  d = csub(b1, xx);
}

template <int L>
__device__ __forceinline__ void dif16(C2* z, int tid, const float4* __restrict__ twg4) {
  const int Q = 1 << (L - 2);
  const int pos2 = tid & (Q - 1);
  const int i0 = ((tid >> (L - 2)) << (L + 2)) | pos2;
  int ad[16]; C2 x[16];
#pragma unroll
  for (int k = 0; k < 16; ++k) { ad[k] = swz(i0 + k * Q); x[k] = z[ad[k]]; }
#pragma unroll
  for (int r = 0; r < 4; ++r)
    dif4(x[r], x[r + 4], x[r + 8], x[r + 12], twg4[(pos2 + r * Q) << (11 - L)]);
  {
    float4 wv2 = twg4[pos2 << (13 - L)];
#pragma unroll
    for (int m = 0; m < 4; ++m)
      dif4(x[4 * m], x[4 * m + 1], x[4 * m + 2], x[4 * m + 3], wv2);
  }
#pragma unroll
  for (int k = 0; k < 16; ++k) z[ad[k]] = x[k];
}
template <int L>
__device__ __forceinline__ void dit16(C2* z, int tid, const float4* __restrict__ twg4) {
  const int Q = 1 << (L - 2);
  const int pos2 = tid & (Q - 1);
  const int i0 = ((tid >> (L - 2)) << (L + 2)) | pos2;
  int ad[16]; C2 x[16];
#pragma unroll
  for (int k = 0; k < 16; ++k) { ad[k] = swz(i0 + k * Q); x[k] = z[ad[k]]; }
  {
    float4 wv2 = twg4[pos2 << (13 - L)];
#pragma unroll
    for (int m = 0; m < 4; ++m)
      dit4(x[4 * m], x[4 * m + 1], x[4 * m + 2], x[4 * m + 3], wv2);
  }
#pragma unroll
  for (int r = 0; r < 4; ++r)
    dit4(x[r], x[r + 4], x[r + 8], x[r + 12], twg4[(pos2 + r * Q) << (11 - L)]);
#pragma unroll
  for (int k = 0; k < 16; ++k) z[ad[k]] = x[k];
}

template <int LOGM>
__device__ __forceinline__ void dif_pass(C2* z, int tid, const float4* __restrict__ twg4) {
  const int M4 = 1 << LOGM;
#pragma unroll
  for (int j = 0; j < 4; ++j) {
    int b = tid + j * 512;
    int pos = b & (M4 - 1);
    int i0 = ((b >> LOGM) << (LOGM + 2)) | pos;
    int ia = swz(i0), ib = swz(i0 + M4), ic = swz(i0 + 2 * M4), id = swz(i0 + 3 * M4);
    C2 a = z[ia], bb = z[ib], c = z[ic], d = z[id];
    float4 wv = twg4[pos << (11 - LOGM)];
    dif4(a, bb, c, d, wv);
    z[ia] = a; z[ib] = bb; z[ic] = c; z[id] = d;
  }
}

template <int LOGM>
__device__ __forceinline__ void dit_pass(C2* z, int tid, const float4* __restrict__ twg4) {
  const int M4 = 1 << LOGM;
#pragma unroll
  for (int j = 0; j < 4; ++j) {
    int b = tid + j * 512;
    int pos = b & (M4 - 1);
    int i0 = ((b >> LOGM) << (LOGM + 2)) | pos;
    int ia = swz(i0), ib = swz(i0 + M4), ic = swz(i0 + 2 * M4), id = swz(i0 + 3 * M4);
    C2 a = z[ia], bb = z[ib], c = z[ic], d = z[id];
    float4 wv = twg4[pos << (11 - LOGM)];
    dit4(a, bb, c, d, wv);
    z[ia] = a; z[ib] = bb; z[ic] = c; z[id] = d;
  }
}

__device__ __forceinline__ void dif_r8(C2* z, int tid) {
#pragma unroll
  for (int j = 0; j < 2; ++j) {
    int base = (tid + j * 512) << 3;
    int ad[8]; C2 x[8];
#pragma unroll
    for (int e = 0; e < 8; ++e) { ad[e] = swz(base + e); x[e] = z[ad[e]]; }
    C2 t;
    t = csub(x[0], x[4]); x[0] = cadd(x[0], x[4]); x[4] = t;
    t = csub(x[1], x[5]); x[1] = cadd(x[1], x[5]); x[5] = cmul(t, {RS, -RS});
    t = csub(x[2], x[6]); x[2] = cadd(x[2], x[6]); x[6] = cmulni(t);
    t = csub(x[3], x[7]); x[3] = cadd(x[3], x[7]); x[7] = cmul(t, {-RS, -RS});
    t = csub(x[0], x[2]); x[0] = cadd(x[0], x[2]); x[2] = t;
    t = csub(x[1], x[3]); x[1] = cadd(x[1], x[3]); x[3] = cmulni(t);
    t = csub(x[4], x[6]); x[4] = cadd(x[4], x[6]); x[6] = t;
    t = csub(x[5], x[7]); x[5] = cadd(x[5], x[7]); x[7] = cmulni(t);
    t = csub(x[0], x[1]); x[0] = cadd(x[0], x[1]); x[1] = t;
    t = csub(x[2], x[3]); x[2] = cadd(x[2], x[3]); x[3] = t;
    t = csub(x[4], x[5]); x[4] = cadd(x[4], x[5]); x[5] = t;
    t = csub(x[6], x[7]); x[6] = cadd(x[6], x[7]); x[7] = t;
#pragma unroll
    for (int e = 0; e < 8; ++e) z[ad[e]] = x[e];
  }
}

__device__ __forceinline__ void r8_fused(C2* z, int tid, const u32* __restrict__ kfr) {
#pragma unroll
  for (int j = 0; j < 2; ++j) {
    int base = (tid + j * 512) << 3;
    int ad[8]; C2 x[8];
#pragma unroll
    for (int e = 0; e < 8; ++e) { ad[e] = swz(base + e); x[e] = z[ad[e]]; }
    u32x4 k0 = *(const u32x4*)(kfr + base);
    u32x4 k1 = *(const u32x4*)(kfr + base + 4);
    u32 kw[8] = {k0[0], k0[1], k0[2], k0[3], k1[0], k1[1], k1[2], k1[3]};
    C2 t;
    t = csub(x[0], x[4]); x[0] = cadd(x[0], x[4]); x[4] = t;
    t = csub(x[1], x[5]); x[1] = cadd(x[1], x[5]); x[5] = cmul(t, {RS, -RS});
    t = csub(x[2], x[6]); x[2] = cadd(x[2], x[6]); x[6] = cmulni(t);
    t = csub(x[3], x[7]); x[3] = cadd(x[3], x[7]); x[7] = cmul(t, {-RS, -RS});
    t = csub(x[0], x[2]); x[0] = cadd(x[0], x[2]); x[2] = t;
    t = csub(x[1], x[3]); x[1] = cadd(x[1], x[3]); x[3] = cmulni(t);
    t = csub(x[4], x[6]); x[4] = cadd(x[4], x[6]); x[6] = t;
    t = csub(x[5], x[7]); x[5] = cadd(x[5], x[7]); x[7] = cmulni(t);
    t = csub(x[0], x[1]); x[0] = cadd(x[0], x[1]); x[1] = t;
    t = csub(x[2], x[3]); x[2] = cadd(x[2], x[3]); x[3] = t;
    t = csub(x[4], x[5]); x[4] = cadd(x[4], x[5]); x[5] = t;
    t = csub(x[6], x[7]); x[6] = cadd(x[6], x[7]); x[7] = t;
#pragma unroll
    for (int e = 0; e < 8; ++e) {
      C2 kf = {bf2f((u16)(kw[e] & 0xffffu)), bf2f((u16)(kw[e] >> 16))};
      C2 pr = cmul(x[e], kf);
      x[e] = {pr.x, -pr.y};
    }
    t = x[1]; x[1] = csub(x[0], t); x[0] = cadd(x[0], t);
    t = x[3]; x[3] = csub(x[2], t); x[2] = cadd(x[2], t);
    t = x[5]; x[5] = csub(x[4], t); x[4] = cadd(x[4], t);
    t = x[7]; x[7] = csub(x[6], t); x[6] = cadd(x[6], t);
    t = x[2];          x[2] = csub(x[0], t); x[0] = cadd(x[0], t);
    t = cmulni(x[3]);  x[3] = csub(x[1], t); x[1] = cadd(x[1], t);
    t = x[6];          x[6] = csub(x[4], t); x[4] = cadd(x[4], t);
    t = cmulni(x[7]);  x[7] = csub(x[5], t); x[5] = cadd(x[5], t);
    t = x[4];                    x[4] = csub(x[0], t); x[0] = cadd(x[0], t);
    t = cmul(x[5], {RS, -RS});   x[5] = csub(x[1], t); x[1] = cadd(x[1], t);
    t = cmulni(x[6]);            x[6] = csub(x[2], t); x[2] = cadd(x[2], t);
    t = cmul(x[7], {-RS, -RS});  x[7] = csub(x[3], t); x[3] = cadd(x[3], t);
#pragma unroll
    for (int e = 0; e < 8; ++e) z[ad[e]] = x[e];
  }
}

__global__ __launch_bounds__(512) void kfft2(
    const u16* __restrict__ KTb, const float4* __restrict__ twg4,
    u32* __restrict__ Kfb) {
  __shared__ C2 z[8192];
  const int g = blockIdx.x;
  const int t = threadIdx.x;
  const u16* k0r = KTb + ((size_t)(2 * g) << 12);
  const u16* k1r = KTb + ((size_t)(2 * g + 1) << 12);

  C2 x[16];
#pragma unroll
  for (int k = 0; k < 8; ++k) {
    int l = t + k * 512;
    x[k] = {bf2f(k0r[l]), bf2f(k1r[l])};
  }
#pragma unroll
  for (int k = 8; k < 16; ++k) x[k] = {0.f, 0.f};
#pragma unroll
  for (int r = 0; r < 4; ++r)
    dif4(x[r], x[r + 4], x[r + 8], x[r + 12], twg4[t + r * 512]);
  {
    float4 wv2 = twg4[t << 2];
#pragma unroll
    for (int m = 0; m < 4; ++m)
      dif4(x[4 * m], x[4 * m + 1], x[4 * m + 2], x[4 * m + 3], wv2);
  }
#pragma unroll
  for (int k = 0; k < 16; ++k) z[swz(t + k * 512)] = x[k];
  __syncthreads();

  dif16<7>(z, t, twg4);   __syncthreads();
  dif_pass<3>(z, t, twg4); __syncthreads();
  dif_r8(z, t);            __syncthreads();

  u32* o0 = Kfb + ((size_t)(2 * g) << 13);
  u32* o1 = Kfb + ((size_t)(2 * g + 1) << 13);
#pragma unroll
  for (int it = 0; it < 16; ++it) {
    int p = t + it * 512;
    int k = BR13(p);
    int km = (8192 - k) & 8191;
    int p2 = BR13(km);
    C2 Zk = z[swz(p)], Zm = z[swz(p2)];
    float f0r = 0.5f * (Zk.x + Zm.x), f0i = 0.5f * (Zk.y - Zm.y);
    float f1r = 0.5f * (Zk.y + Zm.y), f1i = 0.5f * (Zm.x - Zk.x);
    o0[p] = (u32)f2bf(f0r) | ((u32)f2bf(f0i) << 16);
    o1[p] = (u32)f2bf(f1r) | ((u32)f2bf(f1i) << 16);
  }
}

__global__ __launch_bounds__(512) void fft_conv4(
    const u16* __restrict__ xdTb, const u32* __restrict__ Kfb,
    const float* __restrict__ meanv, const float* __restrict__ invv,
    const float* __restrict__ n2w, const float* __restrict__ n2b,
    const float* __restrict__ Dv, const float4* __restrict__ twg4,
    u16* __restrict__ dT) {
  __shared__ C2 z[8192];
  const int h = blockIdx.x;
  const int t = threadIdx.x;
  const u16* xr = xdTb + ((size_t)h << 13);
  const float w2h = n2w[h], b2h = n2b[h], Dh = Dv[h];

  float xn0r[8], xn1r[8];
  C2 x[16];
#pragma unroll
  for (int k = 0; k < 8; ++k) {
    int l = t + k * 512;
    float x0 = bf2f(xr[l]);
    float x1 = bf2f(xr[4096 + l]);
    xn0r[k] = (x0 - meanv[l]) * invv[l] * w2h + b2h;
    xn1r[k] = (x1 - meanv[4096 + l]) * invv[4096 + l] * w2h + b2h;
    x[k] = {xn0r[k], xn1r[k]};
  }
#pragma unroll
  for (int k = 8; k < 16; ++k) x[k] = {0.f, 0.f};
#pragma unroll
  for (int r = 0; r < 4; ++r)
    dif4(x[r], x[r + 4], x[r + 8], x[r + 12], twg4[t + r * 512]);
  {
    float4 wv2 = twg4[t << 2];
#pragma unroll
    for (int m = 0; m < 4; ++m)
      dif4(x[4 * m], x[4 * m + 1], x[4 * m + 2], x[4 * m + 3], wv2);
  }
#pragma unroll
  for (int k = 0; k < 16; ++k) z[swz(t + k * 512)] = x[k];
  __syncthreads();

  dif16<7>(z, t, twg4);    __syncthreads();
  dif_pass<3>(z, t, twg4);  __syncthreads();
  r8_fused(z, t, Kfb + ((size_t)h << 13)); __syncthreads();
  dit_pass<3>(z, t, twg4);  __syncthreads();
  dit16<7>(z, t, twg4);     __syncthreads();

#pragma unroll
  for (int k = 0; k < 16; ++k) x[k] = z[swz(t + k * 512)];
  {
    float4 wv2 = twg4[t << 2];
#pragma unroll
    for (int m = 0; m < 4; ++m)
      dit4(x[4 * m], x[4 * m + 1], x[4 * m + 2], x[4 * m + 3], wv2);
  }
  const float sc = 1.0f / 8192.0f;
  u16* drow = dT + ((size_t)h << 13);
#pragma unroll
  for (int r = 0; r < 4; ++r) {
    float4 wv = twg4[t + r * 512];
    C2 w = {wv.x, wv.y}, wm = {wv.y, -wv.x}, wa = {wv.z, wv.w};
    C2 a = x[r], bb = x[r + 4], c = x[r + 8], d = x[r + 12];
    C2 tt = cmul(wa, bb);
    C2 a1 = cadd(a, tt), b1 = csub(a, tt);
    C2 u = cmul(wa, d);
    C2 c1 = cadd(c, u), d1 = csub(c, u);
    C2 olo = cadd(a1, cmul(w, c1));
    C2 ohi = cadd(b1, cmul(wm, d1));
    int l0 = t + r * 512;
    int l1 = t + (r + 4) * 512;
    drow[l0] = f2bf(fmaf(Dh, xn0r[r], olo.x * sc));
    drow[4096 + l0] = f2bf(fmaf(Dh, xn1r[r], -olo.y * sc));
    drow[l1] = f2bf(fmaf(Dh, xn0r[r + 4], ohi.x * sc));
    drow[4096 + l1] = f2bf(fmaf(Dh, xn1r[r + 4], -ohi.y * sc));
  }
}

// ---------------------------------------------------------------- launch
extern "C" void kernel_launch(void* const* d_in, const int* in_sizes, int n_in,
                              void* d_out, int out_size, void* d_ws, size_t ws_size,
                              hipStream_t stream) {
  (void)in_sizes; (void)n_in; (void)out_size; (void)ws_size;
  const float* idx  = (const float*)d_in[0];
  const float* n1w  = (const float*)d_in[1];
  const float* n1b  = (const float*)d_in[2];
  const float* Wxg  = (const float*)d_in[3];
  const float* Wdin = (const float*)d_in[4];
  const float* n2w  = (const float*)d_in[5];
  const float* n2b  = (const float*)d_in[6];
  const float* LR   = (const float*)d_in[7];
  const float* LI   = (const float*)d_in[8];
  const float* CR   = (const float*)d_in[9];
  const float* CI   = (const float*)d_in[10];
  const float* Dv   = (const float*)d_in[11];
  const float* Wgate= (const float*)d_in[12];
  const float* Wout = (const float*)d_in[13];
  const float* bout = (const float*)d_in[14];
  float* out = (float*)d_out;

  const int L = 4096, DIM = 1024, HID = 4096, H = 512;
  const int M = 8192;

  char* p = (char*)d_ws;
  auto alloc = [&](size_t bytes) { char* q = p; p += (bytes + 255) & ~(size_t)255; return q; };
  u16* Wxg_t   = (u16*)alloc((size_t)HID * DIM * 2);
  u16* Wdin_t  = (u16*)alloc((size_t)H * DIM * 2);
  u16* Wgate_t = (u16*)alloc((size_t)HID * H * 2);
  u16* Wout_t  = (u16*)alloc((size_t)DIM * HID * 2);
  u16* xbf     = (u16*)alloc((size_t)M * DIM * 2);
  u16* ebuf    = (u16*)alloc((size_t)M * HID * 2);
  u16* xdTb    = (u16*)alloc((size_t)H * M * 2);
  float* meanv = (float*)alloc((size_t)M * 4);
  float* invv  = (float*)alloc((size_t)M * 4);
  u16* SRSI    = (u16*)alloc((size_t)L * 1024 * 2);
  u16* Ct      = (u16*)alloc((size_t)H * 1024 * 2);
  u16* KTb     = (u16*)alloc((size_t)H * L * 2);
  u16* dTm     = (u16*)alloc((size_t)H * M * 2);
  u16* dbuf    = (u16*)alloc((size_t)M * H * 2);
  float4* twg4 = (float4*)alloc((size_t)2048 * 16);
  u32* Kfb     = (u32*)alloc((size_t)H * M * 4);
  double* aexp = (double*)alloc((size_t)512 * 8);
  double* fexp = (double*)alloc((size_t)512 * 8);

  // 1) mega1: LN1 + 4x weight transpose + twiddle + kgen_c + exp tables
  mega1<<<dim3(8192 + 4096 + 4096 + 2048 + 512 + 1024 + 8 + 2), 256, 0, stream>>>(
      idx, n1w, n1b, Wxg, Wdin, Wgate, Wout,
      Wxg_t, Wdin_t, Wgate_t, Wout_t, xbf, twg4, LR, LI, CR, CI, Ct, aexp, fexp);
  // 2) SRSI
  kgen_s2<<<dim3(L * 1024 / 256), 256, 0, stream>>>(aexp, fexp, SRSI);
  // 3) xd^T = Wdin_t @ xbf^T  bf16 [512][8192], grid 256
  gemm128s<1><<<dim3((H / 128) * (M / 128)), 256, 0, stream>>>(
      Wdin_t, xbf, H, M, DIM, nullptr, xdTb, nullptr, nullptr);
  // 4) l3mix: K^T gemm + LN2 stats
  l3mix<<<dim3(256), 256, 0, stream>>>(Ct, SRSI, KTb, xdTb, meanv, invv);
  // 5) Kf spectra
  kfft2<<<dim3(H / 2), 512, 0, stream>>>(KTb, twg4, Kfb);
  // 6) packed FFT conv -> d^T
  fft_conv4<<<dim3(H), 512, 0, stream>>>(xdTb, Kfb, meanv, invv, n2w, n2b, Dv, twg4, dTm);
  // 7) d^T -> d
  trans_bf<<<dim3((H / 32) * (M / 32)), 256, 0, stream>>>(dTm, dbuf, H, M);
  // 8) e = (x@Wxg) * (d@Wgate)
  gemm_fuse2<<<dim3((M / 128) * (HID / 128)), 256, 0, stream>>>(
      xbf, Wxg_t, DIM, dbuf, Wgate_t, H, M, HID, ebuf);
  // 9) out = e @ Wout + bout + idx
  gemm128s<3><<<dim3((M / 128) * (DIM / 128)), 256, 0, stream>>>(
      ebuf, Wout_t, M, DIM, HID, out, nullptr, bout, idx);
}

// Round 16
// 310.805 us; speedup vs baseline: 1.0686x; 1.0686x over previous
//
#include <hip/hip_runtime.h>
#include <math.h>

// GSS block on MI355X. Shapes: B=2, L=4096, DIM=1024, HID=4096, H=DSSH=512, N=DSSN=512.
// R16 = R13 revert (best passing: 311.6 us). R15's ring pipeline regressed
// (4-slot swizzle -> 8-way LDS bank conflict, 1.26e7/dispatch; 2x barriers at
// BK=32). 2-phase BK=64 gemm128p + gemm_fuse2 + mega1 + fused-radix FFT.

typedef unsigned short u16;
typedef unsigned int u32;
typedef __attribute__((ext_vector_type(8))) __bf16 bf16x8;
typedef __attribute__((ext_vector_type(4))) float f32x4;
typedef __attribute__((ext_vector_type(4))) u32 u32x4;

__device__ __forceinline__ u16 f2bf(float f) {
  u32 u = __float_as_uint(f);
  u32 r = u + 0x7FFFu + ((u >> 16) & 1u);
  return (u16)(r >> 16);
}
__device__ __forceinline__ float bf2f(u16 h) { return __uint_as_float(((u32)h) << 16); }

// ================================================================ device bodies
__device__ __forceinline__ void trans_conv_body(
    int bid, const float* __restrict__ in, u16* __restrict__ out, int K, int N,
    float (*t)[33]) {
  int tx = threadIdx.x & 31, ty = threadIdx.x >> 5;
  int nb = N >> 5;
  int k0 = (bid / nb) << 5;
  int n0 = (bid % nb) << 5;
#pragma unroll
  for (int i = 0; i < 32; i += 8)
    t[ty + i][tx] = in[(size_t)(k0 + ty + i) * N + n0 + tx];
  __syncthreads();
#pragma unroll
  for (int i = 0; i < 32; i += 8)
    out[(size_t)(n0 + ty + i) * K + k0 + tx] = f2bf(t[tx][ty + i]);
}

__device__ __forceinline__ void ln1_body(
    int bid, const float* __restrict__ in, const float* __restrict__ gw,
    const float* __restrict__ gb, u16* __restrict__ outp, float* sbuf) {
  const int D = 1024;
  int tid = threadIdx.x;
  const float4* r4 = (const float4*)(in + (size_t)bid * D);
  float4 v = r4[tid];
  float s = v.x + v.y + v.z + v.w;
  float ss = fmaf(v.x, v.x, fmaf(v.y, v.y, fmaf(v.z, v.z, v.w * v.w)));
#pragma unroll
  for (int o = 32; o >= 1; o >>= 1) { s += __shfl_xor(s, o); ss += __shfl_xor(ss, o); }
  float* sa = sbuf;
  float* sb = sbuf + 8;
  if ((tid & 63) == 0) { sa[tid >> 6] = s; sb[tid >> 6] = ss; }
  __syncthreads();
  float S = sa[0] + sa[1] + sa[2] + sa[3];
  float SS = sb[0] + sb[1] + sb[2] + sb[3];
  float mean = S / (float)D;
  float var = SS / (float)D - mean * mean;
  float inv = rsqrtf(var + 1e-5f);
  float4 wv = ((const float4*)gw)[tid];
  float4 bv = ((const float4*)gb)[tid];
  ushort4 o;
  o.x = f2bf((v.x - mean) * inv * wv.x + bv.x);
  o.y = f2bf((v.y - mean) * inv * wv.y + bv.y);
  o.z = f2bf((v.z - mean) * inv * wv.z + bv.z);
  o.w = f2bf((v.w - mean) * inv * wv.w + bv.w);
  ((ushort4*)outp)[(size_t)bid * (D >> 2) + tid] = o;
}

__device__ __forceinline__ void kgen_c_body(
    int bid, const float* __restrict__ LR, const float* __restrict__ LI,
    const float* __restrict__ CR, const float* __restrict__ CI, u16* __restrict__ Ct) {
  int idx0 = bid * 256 + threadIdx.x;  // over 512*512
  int h = idx0 >> 9, n = idx0 & 511;
  float eLR = expf(LR[n]), eLI = expf(LI[n]);
  float lre = -eLR, lim = eLI;
  float er = expf(lre);
  float c, s;
  sincosf(lim, &s, &c);
  float wr = er * c - 1.0f, wi = er * s;
  float den = lre * lre + lim * lim;
  float gr = (wr * lre + wi * lim) / den;
  float gi = (wi * lre - wr * lim) / den;
  float cr = CR[(size_t)h * 512 + n], ci = CI[(size_t)h * 512 + n];
  float ccr = cr * gr - ci * gi;
  float cci = cr * gi + ci * gr;
  Ct[(size_t)h * 1024 + n] = f2bf(ccr);
  Ct[(size_t)h * 1024 + 512 + n] = f2bf(-cci);
}

__device__ __forceinline__ void twfill_body(int bid, float4* __restrict__ twg4) {
  int j = bid * 256 + threadIdx.x;
  float t1 = -6.2831853071795864769f * (float)j / 8192.0f;
  float s1, c1, s2, c2;
  sincosf(t1, &s1, &c1);
  sincosf(2.0f * t1, &s2, &c2);
  twg4[j] = {c1, s1, c2, s2};
}

__device__ __forceinline__ void tab_body(
    int bid, const float* __restrict__ LR, const float* __restrict__ LI,
    double* __restrict__ aexp, double* __restrict__ fexp) {
  int n = bid * 256 + threadIdx.x;
  if (n < 512) {
    aexp[n] = exp((double)LR[n]);
    fexp[n] = exp((double)LI[n]) * 0.15915494309189533577;  // 1/(2*pi)
  }
}

__device__ __forceinline__ void ln_stats_body(
    int bid, const u16* __restrict__ xdTb, float* __restrict__ meanv,
    float* __restrict__ invv, float* sbuf) {
  int lane = threadIdx.x & 63;
  int seg = threadIdx.x >> 6;
  int col = bid * 64 + lane;
  float s = 0.f, ss = 0.f;
  const u16* p = xdTb + (size_t)(seg * 128) * 8192 + col;
#pragma unroll 8
  for (int r = 0; r < 128; ++r) {
    float v = bf2f(p[(size_t)r * 8192]);
    s += v; ss = fmaf(v, v, ss);
  }
  float* sa = sbuf;           // [4][64]
  float* sb = sbuf + 256;     // [4][64]
  sa[seg * 64 + lane] = s; sb[seg * 64 + lane] = ss;
  __syncthreads();
  if (threadIdx.x < 64) {
    float S = sa[lane] + sa[64 + lane] + sa[128 + lane] + sa[192 + lane];
    float SS = sb[lane] + sb[64 + lane] + sb[128 + lane] + sb[192 + lane];
    float mean = S * (1.0f / 512.0f);
    float var = SS * (1.0f / 512.0f) - mean * mean;
    meanv[bid * 64 + lane] = mean;
    invv[bid * 64 + lane] = rsqrtf(var + 1e-5f);
  }
}

// ---------------------------------------------------------------- 128x128 GEMM body
// MODE 1: bf16 out   3: f32 C+bias[n]+res[m,n]. lds: 2*16384 u16 (64 KiB).
template <int MODE>
__device__ __forceinline__ void gemm128p_body(
    int bid0, int nwg, const u16* __restrict__ A, const u16* __restrict__ Bt,
    int M, int N, int K, float* Cf, u16* Cb,
    const float* __restrict__ bias, const float* __restrict__ res, u16* lds) {
  constexpr int BUF = 16384;
  const int tid = threadIdx.x;
  const int lane = tid & 63;
  const int w = tid >> 6;
  const int cpx = nwg >> 3;
  const int bid = (nwg & 7) ? bid0 : (bid0 & 7) * cpx + (bid0 >> 3);
  const int tiles_n = N >> 7;
  const int tm = (bid / tiles_n) << 7;
  const int tn = (bid % tiles_n) << 7;

  const int wm = w >> 1, wn = w & 1;
  const int lr = lane & 15;
  const int kq = lane >> 4;
  const int l7 = lane & 7;
  const int rsub = lane >> 3;
  const int sslot = (lane & 7) ^ rsub;
  const u16* gA = A + (size_t)(tm + w * 32 + rsub) * K + sslot * 8;
  const u16* gB = Bt + (size_t)(tn + w * 32 + rsub) * K + sslot * 8;
  auto ldsc = (__attribute__((address_space(3))) char*)lds;

#define STAGE128(kt, c)                                                                   \
  {                                                                                       \
    const size_t kof = (size_t)(kt) << 6;                                                 \
    _Pragma("unroll") for (int i = 0; i < 4; ++i) {                                       \
      u32 da = (u32)((c)*BUF + (w * 32 + i * 8) * 64) * 2u;                               \
      __builtin_amdgcn_global_load_lds(                                                   \
          (const __attribute__((address_space(1))) void*)(gA + (size_t)(i * 8) * K + kof),\
          (__attribute__((address_space(3))) void*)(ldsc + da), 16, 0, 0);                \
      __builtin_amdgcn_global_load_lds(                                                   \
          (const __attribute__((address_space(1))) void*)(gB + (size_t)(i * 8) * K + kof),\
          (__attribute__((address_space(3))) void*)(ldsc + da + 16384), 16, 0, 0);        \
    }                                                                                     \
  }

  f32x4 acc[4][4] = {};
  const int NT = K >> 6;

  STAGE128(0, 0);
  asm volatile("s_waitcnt vmcnt(0)" ::: "memory");
  __builtin_amdgcn_s_barrier();
  __builtin_amdgcn_sched_barrier(0);

  int cur = 0;
  for (int kt = 0; kt < NT; ++kt) {
    if (kt + 1 < NT) STAGE128(kt + 1, cur ^ 1);
    const u32 ab = (u32)cur * BUF;
#pragma unroll
    for (int ks = 0; ks < 2; ++ks) {
      const int slp = ((((ks << 2) | kq)) ^ l7) << 3;
      bf16x8 af[4], bv[4];
#pragma unroll
      for (int mi = 0; mi < 4; ++mi) {
        int ra = wm * 64 + mi * 16 + lr;
        af[mi] = *(const bf16x8*)&lds[ab + ra * 64 + slp];
      }
#pragma unroll
      for (int ni = 0; ni < 4; ++ni) {
        int rb = wn * 64 + ni * 16 + lr;
        bv[ni] = *(const bf16x8*)&lds[ab + 8192 + rb * 64 + slp];
      }
      __builtin_amdgcn_s_setprio(1);
#pragma unroll
      for (int mi = 0; mi < 4; ++mi)
#pragma unroll
        for (int ni = 0; ni < 4; ++ni)
          acc[mi][ni] = __builtin_amdgcn_mfma_f32_16x16x32_bf16(af[mi], bv[ni], acc[mi][ni], 0, 0, 0);
      __builtin_amdgcn_s_setprio(0);
    }
    asm volatile("s_waitcnt vmcnt(0)" ::: "memory");
    __builtin_amdgcn_s_barrier();
    __builtin_amdgcn_sched_barrier(0);
    cur ^= 1;
  }
#undef STAGE128

  // ---- LDS-shuffle epilogue
  float* lf = (float*)lds + w * (16 * 68);
  const int er = lane >> 2;
  const int ec = (lane & 3) << 4;
  const int gcol = tn + wn * 64 + ec;
#pragma unroll
  for (int mi = 0; mi < 4; ++mi) {
#pragma unroll
    for (int ni = 0; ni < 4; ++ni)
#pragma unroll
      for (int j = 0; j < 4; ++j)
        lf[(kq * 4 + j) * 68 + ni * 16 + lr] = acc[mi][ni][j];
    float v[16];
#pragma unroll
    for (int q = 0; q < 4; ++q)
      *(f32x4*)&v[q * 4] = *(const f32x4*)&lf[er * 68 + ec + q * 4];
    const int gr = tm + wm * 64 + mi * 16 + er;
    if (MODE == 3) {
      const float* rr = res + (size_t)gr * N + gcol;
      const float* br = bias + gcol;
      float* orr = Cf + (size_t)gr * N + gcol;
#pragma unroll
      for (int q = 0; q < 4; ++q) {
        f32x4 rv = *(const f32x4*)(rr + q * 4);
        f32x4 bv4 = *(const f32x4*)(br + q * 4);
        f32x4 ov;
        ov[0] = v[q * 4 + 0] + bv4[0] + rv[0];
        ov[1] = v[q * 4 + 1] + bv4[1] + rv[1];
        ov[2] = v[q * 4 + 2] + bv4[2] + rv[2];
        ov[3] = v[q * 4 + 3] + bv4[3] + rv[3];
        *(f32x4*)(orr + q * 4) = ov;
      }
    } else {
      u32 pk[8];
#pragma unroll
      for (int e = 0; e < 8; ++e)
        pk[e] = (u32)f2bf(v[2 * e]) | ((u32)f2bf(v[2 * e + 1]) << 16);
      u16* orr = Cb + (size_t)gr * N + gcol;
      *(u32x4*)orr = u32x4{pk[0], pk[1], pk[2], pk[3]};
      *(u32x4*)(orr + 8) = u32x4{pk[4], pk[5], pk[6], pk[7]};
    }
  }
}

// ================================================================ kernels

// mega1: LN1 (8192) | Wxg (4096) | Wout (4096) | Wgate (2048) | Wdin (512) |
//        kgen_c (1024) | twfill (8) | tables (2). 256 threads.
__global__ __launch_bounds__(256) void mega1(
    const float* __restrict__ idxf, const float* __restrict__ n1w, const float* __restrict__ n1b,
    const float* __restrict__ Wxg, const float* __restrict__ Wdin,
    const float* __restrict__ Wgate, const float* __restrict__ Wout,
    u16* __restrict__ Wxg_t, u16* __restrict__ Wdin_t,
    u16* __restrict__ Wgate_t, u16* __restrict__ Wout_t,
    u16* __restrict__ xbf, float4* __restrict__ twg4,
    const float* __restrict__ LR, const float* __restrict__ LI,
    const float* __restrict__ CR, const float* __restrict__ CI,
    u16* __restrict__ Ct, double* __restrict__ aexp, double* __restrict__ fexp) {
  __shared__ __align__(16) char smem[4352];
  int b = (int)blockIdx.x;
  if (b < 8192) { ln1_body(b, idxf, n1w, n1b, xbf, (float*)smem); return; }
  b -= 8192;
  if (b < 4096) { trans_conv_body(b, Wxg, Wxg_t, 1024, 4096, (float(*)[33])smem); return; }
  b -= 4096;
  if (b < 4096) { trans_conv_body(b, Wout, Wout_t, 4096, 1024, (float(*)[33])smem); return; }
  b -= 4096;
  if (b < 2048) { trans_conv_body(b, Wgate, Wgate_t, 512, 4096, (float(*)[33])smem); return; }
  b -= 2048;
  if (b < 512) { trans_conv_body(b, Wdin, Wdin_t, 1024, 512, (float(*)[33])smem); return; }
  b -= 512;
  if (b < 1024) { kgen_c_body(b, LR, LI, CR, CI, Ct); return; }
  b -= 1024;
  if (b < 8) { twfill_body(b, twg4); return; }
  b -= 8;
  tab_body(b, LR, LI, aexp, fexp);
}

// kgen_s2: SRSI[l][kk] from tables; hardware trig in revolutions.
__global__ __launch_bounds__(256) void kgen_s2(
    const double* __restrict__ aexp, const double* __restrict__ fexp,
    u16* __restrict__ SRSI) {
  int idx0 = (int)blockIdx.x * 256 + threadIdx.x;
  int l = idx0 >> 10;
  int kk = idx0 & 1023;
  int n = kk & 511;
  double fl = fexp[n] * (double)l;
  float rev = (float)(fl - floor(fl));
  float tri = (kk < 512) ? __builtin_amdgcn_cosf(rev) : __builtin_amdgcn_sinf(rev);
  float al = (float)aexp[n] * (float)l;
  SRSI[idx0] = f2bf(expf(-al) * tri);
}

// standalone GEMM wrapper
template <int MODE>
__global__ __launch_bounds__(256, 2) void gemm128p(
    const u16* __restrict__ A, const u16* __restrict__ Bt,
    int M, int N, int K,
    float* Cf, u16* Cb,
    const float* __restrict__ bias, const float* __restrict__ res) {
  __shared__ __align__(16) u16 lds[2 * 16384];
  gemm128p_body<MODE>((int)blockIdx.x, (int)gridDim.x, A, Bt, M, N, K, Cf, Cb, bias, res, lds);
}

// l3mix: blocks [0,128) -> KT-gemm (bf16), [128,256) -> ln_stats.
__global__ __launch_bounds__(256, 2) void l3mix(
    const u16* __restrict__ Ct, const u16* __restrict__ SRSI, u16* __restrict__ KTb,
    const u16* __restrict__ xdTb, float* __restrict__ meanv, float* __restrict__ invv) {
  __shared__ __align__(16) u16 lds[2 * 16384];
  int b = (int)blockIdx.x;
  if (b < 128) {
    gemm128p_body<1>(b, 128, Ct, SRSI, 512, 4096, 1024, nullptr, KTb, nullptr, nullptr, lds);
  } else {
    ln_stats_body(b - 128, xdTb, meanv, invv, (float*)lds);
  }
}

// bf16 [R][C] -> bf16 [C][R]
__global__ __launch_bounds__(256) void trans_bf(
    const u16* __restrict__ in, u16* __restrict__ out, int R, int C) {
  __shared__ u16 t[32][34];
  int tx = threadIdx.x & 31, ty = threadIdx.x >> 5;
  int nb = C >> 5;
  int r0 = (blockIdx.x / nb) << 5;
  int c0 = (blockIdx.x % nb) << 5;
#pragma unroll
  for (int i = 0; i < 32; i += 8)
    t[ty + i][tx] = in[(size_t)(r0 + ty + i) * C + c0 + tx];
  __syncthreads();
#pragma unroll
  for (int i = 0; i < 32; i += 8)
    out[(size_t)(c0 + ty + i) * R + r0 + tx] = t[tx][ty + i];
}

// ---------------------------------------------------------------- fused gate GEMM
// e[M,N] = (A1[M,K1]@B1t^T) * (A2[M,K2]@B2t^T), bf16 out.
__global__ __launch_bounds__(256, 2) void gemm_fuse2(
    const u16* __restrict__ A1, const u16* __restrict__ B1t, int K1,
    const u16* __restrict__ A2, const u16* __restrict__ B2t, int K2,
    int M, int N, u16* __restrict__ Cb) {
  constexpr int BUF = 16384;
  __shared__ __align__(16) u16 lds[2 * BUF];
  const int tid = threadIdx.x;
  const int lane = tid & 63;
  const int w = tid >> 6;
  const int nwg = (int)gridDim.x;
  const int cpx = nwg >> 3;
  const int bid = (nwg & 7) ? (int)blockIdx.x
                            : ((int)blockIdx.x & 7) * cpx + ((int)blockIdx.x >> 3);
  const int tiles_n = N >> 7;
  const int tm = (bid / tiles_n) << 7;
  const int tn = (bid % tiles_n) << 7;

  const int wm = w >> 1, wn = w & 1;
  const int lr = lane & 15;
  const int kq = lane >> 4;
  const int l7 = lane & 7;
  const int rsub = lane >> 3;
  const int sslot = (lane & 7) ^ rsub;
  auto ldsc = (__attribute__((address_space(3))) char*)lds;

  f32x4 acc1[4][4] = {};
  f32x4 acc2[4][4] = {};

#define STAGEF(gA, gB, K, kt, c)                                                          \
  {                                                                                       \
    const size_t kof = (size_t)(kt) << 6;                                                 \
    _Pragma("unroll") for (int i = 0; i < 4; ++i) {                                       \
      u32 da = (u32)((c)*BUF + (w * 32 + i * 8) * 64) * 2u;                               \
      __builtin_amdgcn_global_load_lds(                                                   \
          (const __attribute__((address_space(1))) void*)((gA) + (size_t)(i * 8) * (K) + kof), \
          (__attribute__((address_space(3))) void*)(ldsc + da), 16, 0, 0);                \
      __builtin_amdgcn_global_load_lds(                                                   \
          (const __attribute__((address_space(1))) void*)((gB) + (size_t)(i * 8) * (K) + kof), \
          (__attribute__((address_space(3))) void*)(ldsc + da + 16384), 16, 0, 0);        \
    }                                                                                     \
  }

#define KLOOP(gA, gB, K, ACC)                                                             \
  {                                                                                       \
    const int NT = (K) >> 6;                                                              \
    STAGEF(gA, gB, K, 0, 0);                                                              \
    asm volatile("s_waitcnt vmcnt(0)" ::: "memory");                                      \
    __builtin_amdgcn_s_barrier();                                                         \
    __builtin_amdgcn_sched_barrier(0);                                                    \
    int cur = 0;                                                                          \
    for (int kt = 0; kt < NT; ++kt) {                                                     \
      if (kt + 1 < NT) STAGEF(gA, gB, K, kt + 1, cur ^ 1);                                \
      const u32 ab = (u32)cur * BUF;                                                      \
      _Pragma("unroll") for (int ks = 0; ks < 2; ++ks) {                                  \
        const int slp = ((((ks << 2) | kq)) ^ l7) << 3;                                   \
        bf16x8 af[4], bv[4];                                                              \
        _Pragma("unroll") for (int mi = 0; mi < 4; ++mi) {                                \
          int ra = wm * 64 + mi * 16 + lr;                                                \
          af[mi] = *(const bf16x8*)&lds[ab + ra * 64 + slp];                              \
        }                                                                                 \
        _Pragma("unroll") for (int ni = 0; ni < 4; ++ni) {                                \
          int rb = wn * 64 + ni * 16 + lr;                                                \
          bv[ni] = *(const bf16x8*)&lds[ab + 8192 + rb * 64 + slp];                       \
        }                                                                                 \
        __builtin_amdgcn_s_setprio(1);                                                    \
        _Pragma("unroll") for (int mi = 0; mi < 4; ++mi)                                  \
          _Pragma("unroll") for (int ni = 0; ni < 4; ++ni)                                \
            ACC[mi][ni] = __builtin_amdgcn_mfma_f32_16x16x32_bf16(af[mi], bv[ni], ACC[mi][ni], 0, 0, 0); \
        __builtin_amdgcn_s_setprio(0);                                                    \
      }                                                                                   \
      asm volatile("s_waitcnt vmcnt(0)" ::: "memory");                                    \
      __builtin_amdgcn_s_barrier();                                                      \
      __builtin_amdgcn_sched_barrier(0);                                                  \
      cur ^= 1;                                                                           \
    }                                                                                     \
  }

  {
    const u16* gA = A1 + (size_t)(tm + w * 32 + rsub) * K1 + sslot * 8;
    const u16* gB = B1t + (size_t)(tn + w * 32 + rsub) * K1 + sslot * 8;
    KLOOP(gA, gB, K1, acc1);
  }
  {
    const u16* gA = A2 + (size_t)(tm + w * 32 + rsub) * K2 + sslot * 8;
    const u16* gB = B2t + (size_t)(tn + w * 32 + rsub) * K2 + sslot * 8;
    KLOOP(gA, gB, K2, acc2);
  }
#undef KLOOP
#undef STAGEF

#pragma unroll
  for (int mi = 0; mi < 4; ++mi)
#pragma unroll
    for (int ni = 0; ni < 4; ++ni)
#pragma unroll
      for (int j = 0; j < 4; ++j)
        acc1[mi][ni][j] *= acc2[mi][ni][j];

  float* lf = (float*)lds + w * (16 * 68);
  const int er = lane >> 2;
  const int ec = (lane & 3) << 4;
  const int gcol = tn + wn * 64 + ec;
#pragma unroll
  for (int mi = 0; mi < 4; ++mi) {
#pragma unroll
    for (int ni = 0; ni < 4; ++ni)
#pragma unroll
      for (int j = 0; j < 4; ++j)
        lf[(kq * 4 + j) * 68 + ni * 16 + lr] = acc1[mi][ni][j];
    float v[16];
#pragma unroll
    for (int q = 0; q < 4; ++q)
      *(f32x4*)&v[q * 4] = *(const f32x4*)&lf[er * 68 + ec + q * 4];
    const int gr = tm + wm * 64 + mi * 16 + er;
    u32 pk[8];
#pragma unroll
    for (int e = 0; e < 8; ++e)
      pk[e] = (u32)f2bf(v[2 * e]) | ((u32)f2bf(v[2 * e + 1]) << 16);
    u16* orr = Cb + (size_t)gr * N + gcol;
    *(u32x4*)orr = u32x4{pk[0], pk[1], pk[2], pk[3]};
    *(u32x4*)(orr + 8) = u32x4{pk[4], pk[5], pk[6], pk[7]};
  }
}

// ---------------------------------------------------------------- FFT machinery
struct C2 { float x, y; };
__device__ __forceinline__ C2 cadd(C2 a, C2 b) { return {a.x + b.x, a.y + b.y}; }
__device__ __forceinline__ C2 csub(C2 a, C2 b) { return {a.x - b.x, a.y - b.y}; }
__device__ __forceinline__ C2 cmul(C2 a, C2 b) {
  return {a.x * b.x - a.y * b.y, a.x * b.y + a.y * b.x};
}
__device__ __forceinline__ C2 cmulni(C2 a) { return {a.y, -a.x}; }  // * (-i)

__device__ __forceinline__ int swz(int a) {
  return a ^ ((a >> 7) & 15) ^ ((a >> 11) & 3) ^ ((a >> 2) & 8) ^ ((a >> 3) & 2) ^ ((a >> 4) & 4);
}

#define BR13(x) ((int)(__brev((u32)(x)) >> 19))
#define RS 0.70710678118654752f

__device__ __forceinline__ void dif4(C2& a, C2& b, C2& c, C2& d, float4 wv) {
  C2 w = {wv.x, wv.y}, wm = {wv.y, -wv.x}, w2 = {wv.z, wv.w};
  C2 a1 = cadd(a, c);
  C2 c1 = cmul(csub(a, c), w);
  C2 b1 = cadd(b, d);
  C2 d1 = cmul(csub(b, d), wm);
  a = cadd(a1, b1);
  b = cmul(csub(a1, b1), w2);
  c = cadd(c1, d1);
  d = cmul(csub(c1, d1), w2);
}
__device__ __forceinline__ void dit4(C2& a, C2& b, C2& c, C2& d, float4 wv) {
  C2 w = {wv.x, wv.y}, wm = {wv.y, -wv.x}, wa = {wv.z, wv.w};
  C2 t = cmul(wa, b);
  C2 a1 = cadd(a, t), b1 = csub(a, t);
  C2 u = cmul(wa, d);
  C2 c1 = cadd(c, u), d1 = csub(c, u);
  C2 v = cmul(w, c1);
  C2 xx = cmul(wm, d1);
  a = cadd(a1, v);
  c = csub(a1, v);
  b = cadd(b1, xx);
  d = csub(b1, xx);
}

template <int L>
__device__ __forceinline__ void dif16(C2* z, int tid, const float4* __restrict__ twg4) {
  const int Q = 1 << (L - 2);
  const int pos2 = tid & (Q - 1);
  const int i0 = ((tid >> (L - 2)) << (L + 2)) | pos2;
  int ad[16]; C2 x[16];
#pragma unroll
  for (int k = 0; k < 16; ++k) { ad[k] = swz(i0 + k * Q); x[k] = z[ad[k]]; }
#pragma unroll
  for (int r = 0; r < 4; ++r)
    dif4(x[r], x[r + 4], x[r + 8], x[r + 12], twg4[(pos2 + r * Q) << (11 - L)]);
  {
    float4 wv2 = twg4[pos2 << (13 - L)];
#pragma unroll
    for (int m = 0; m < 4; ++m)
      dif4(x[4 * m], x[4 * m + 1], x[4 * m + 2], x[4 * m + 3], wv2);
  }
#pragma unroll
  for (int k = 0; k < 16; ++k) z[ad[k]] = x[k];
}
template <int L>
__device__ __forceinline__ void dit16(C2* z, int tid, const float4* __restrict__ twg4) {
  const int Q = 1 << (L - 2);
  const int pos2 = tid & (Q - 1);
  const int i0 = ((tid >> (L - 2)) << (L + 2)) | pos2;
  int ad[16]; C2 x[16];
#pragma unroll
  for (int k = 0; k < 16; ++k) { ad[k] = swz(i0 + k * Q); x[k] = z[ad[k]]; }
  {
    float4 wv2 = twg4[pos2 << (13 - L)];
#pragma unroll
    for (int m = 0; m < 4; ++m)
      dit4(x[4 * m], x[4 * m + 1], x[4 * m + 2], x[4 * m + 3], wv2);
  }
#pragma unroll
  for (int r = 0; r < 4; ++r)
    dit4(x[r], x[r + 4], x[r + 8], x[r + 12], twg4[(pos2 + r * Q) << (11 - L)]);
#pragma unroll
  for (int k = 0; k < 16; ++k) z[ad[k]] = x[k];
}

template <int LOGM>
__device__ __forceinline__ void dif_pass(C2* z, int tid, const float4* __restrict__ twg4) {
  const int M4 = 1 << LOGM;
#pragma unroll
  for (int j = 0; j < 4; ++j) {
    int b = tid + j * 512;
    int pos = b & (M4 - 1);
    int i0 = ((b >> LOGM) << (LOGM + 2)) | pos;
    int ia = swz(i0), ib = swz(i0 + M4), ic = swz(i0 + 2 * M4), id = swz(i0 + 3 * M4);
    C2 a = z[ia], bb = z[ib], c = z[ic], d = z[id];
    float4 wv = twg4[pos << (11 - LOGM)];
    dif4(a, bb, c, d, wv);
    z[ia] = a; z[ib] = bb; z[ic] = c; z[id] = d;
  }
}

template <int LOGM>
__device__ __forceinline__ void dit_pass(C2* z, int tid, const float4* __restrict__ twg4) {
  const int M4 = 1 << LOGM;
#pragma unroll
  for (int j = 0; j < 4; ++j) {
    int b = tid + j * 512;
    int pos = b & (M4 - 1);
    int i0 = ((b >> LOGM) << (LOGM + 2)) | pos;
    int ia = swz(i0), ib = swz(i0 + M4), ic = swz(i0 + 2 * M4), id = swz(i0 + 3 * M4);
    C2 a = z[ia], bb = z[ib], c = z[ic], d = z[id];
    float4 wv = twg4[pos << (11 - LOGM)];
    dit4(a, bb, c, d, wv);
    z[ia] = a; z[ib] = bb; z[ic] = c; z[id] = d;
  }
}

__device__ __forceinline__ void dif_r8(C2* z, int tid) {
#pragma unroll
  for (int j = 0; j < 2; ++j) {
    int base = (tid + j * 512) << 3;
    int ad[8]; C2 x[8];
#pragma unroll
    for (int e = 0; e < 8; ++e) { ad[e] = swz(base + e); x[e] = z[ad[e]]; }
    C2 t;
    t = csub(x[0], x[4]); x[0] = cadd(x[0], x[4]); x[4] = t;
    t = csub(x[1], x[5]); x[1] = cadd(x[1], x[5]); x[5] = cmul(t, {RS, -RS});
    t = csub(x[2], x[6]); x[2] = cadd(x[2], x[6]); x[6] = cmulni(t);
    t = csub(x[3], x[7]); x[3] = cadd(x[3], x[7]); x[7] = cmul(t, {-RS, -RS});
    t = csub(x[0], x[2]); x[0] = cadd(x[0], x[2]); x[2] = t;
    t = csub(x[1], x[3]); x[1] = cadd(x[1], x[3]); x[3] = cmulni(t);
    t = csub(x[4], x[6]); x[4] = cadd(x[4], x[6]); x[6] = t;
    t = csub(x[5], x[7]); x[5] = cadd(x[5], x[7]); x[7] = cmulni(t);
    t = csub(x[0], x[1]); x[0] = cadd(x[0], x[1]); x[1] = t;
    t = csub(x[2], x[3]); x[2] = cadd(x[2], x[3]); x[3] = t;
    t = csub(x[4], x[5]); x[4] = cadd(x[4], x[5]); x[5] = t;
    t = csub(x[6], x[7]); x[6] = cadd(x[6], x[7]); x[7] = t;
#pragma unroll
    for (int e = 0; e < 8; ++e) z[ad[e]] = x[e];
  }
}

__device__ __forceinline__ void r8_fused(C2* z, int tid, const u32* __restrict__ kfr) {
#pragma unroll
  for (int j = 0; j < 2; ++j) {
    int base = (tid + j * 512) << 3;
    int ad[8]; C2 x[8];
#pragma unroll
    for (int e = 0; e < 8; ++e) { ad[e] = swz(base + e); x[e] = z[ad[e]]; }
    u32x4 k0 = *(const u32x4*)(kfr + base);
    u32x4 k1 = *(const u32x4*)(kfr + base + 4);
    u32 kw[8] = {k0[0], k0[1], k0[2], k0[3], k1[0], k1[1], k1[2], k1[3]};
    C2 t;
    t = csub(x[0], x[4]); x[0] = cadd(x[0], x[4]); x[4] = t;
    t = csub(x[1], x[5]); x[1] = cadd(x[1], x[5]); x[5] = cmul(t, {RS, -RS});
    t = csub(x[2], x[6]); x[2] = cadd(x[2], x[6]); x[6] = cmulni(t);
    t = csub(x[3], x[7]); x[3] = cadd(x[3], x[7]); x[7] = cmul(t, {-RS, -RS});
    t = csub(x[0], x[2]); x[0] = cadd(x[0], x[2]); x[2] = t;
    t = csub(x[1], x[3]); x[1] = cadd(x[1], x[3]); x[3] = cmulni(t);
    t = csub(x[4], x[6]); x[4] = cadd(x[4], x[6]); x[6] = t;
    t = csub(x[5], x[7]); x[5] = cadd(x[5], x[7]); x[7] = cmulni(t);
    t = csub(x[0], x[1]); x[0] = cadd(x[0], x[1]); x[1] = t;
    t = csub(x[2], x[3]); x[2] = cadd(x[2], x[3]); x[3] = t;
    t = csub(x[4], x[5]); x[4] = cadd(x[4], x[5]); x[5] = t;
    t = csub(x[6], x[7]); x[6] = cadd(x[6], x[7]); x[7] = t;
#pragma unroll
    for (int e = 0; e < 8; ++e) {
      C2 kf = {bf2f((u16)(kw[e] & 0xffffu)), bf2f((u16)(kw[e] >> 16))};
      C2 pr = cmul(x[e], kf);
      x[e] = {pr.x, -pr.y};
    }
    t = x[1]; x[1] = csub(x[0], t); x[0] = cadd(x[0], t);
    t = x[3]; x[3] = csub(x[2], t); x[2] = cadd(x[2], t);
    t = x[5]; x[5] = csub(x[4], t); x[4] = cadd(x[4], t);
    t = x[7]; x[7] = csub(x[6], t); x[6] = cadd(x[6], t);
    t = x[2];          x[2] = csub(x[0], t); x[0] = cadd(x[0], t);
    t = cmulni(x[3]);  x[3] = csub(x[1], t); x[1] = cadd(x[1], t);
    t = x[6];          x[6] = csub(x[4], t); x[4] = cadd(x[4], t);
    t = cmulni(x[7]);  x[7] = csub(x[5], t); x[5] = cadd(x[5], t);
    t = x[4];                    x[4] = csub(x[0], t); x[0] = cadd(x[0], t);
    t = cmul(x[5], {RS, -RS});   x[5] = csub(x[1], t); x[1] = cadd(x[1], t);
    t = cmulni(x[6]);            x[6] = csub(x[2], t); x[2] = cadd(x[2], t);
    t = cmul(x[7], {-RS, -RS});  x[7] = csub(x[3], t); x[3] = cadd(x[3], t);
#pragma unroll
    for (int e = 0; e < 8; ++e) z[ad[e]] = x[e];
  }
}

// ---------------------------------------------------------------- K-spectrum kernel
__global__ __launch_bounds__(512) void kfft2(
    const u16* __restrict__ KTb, const float4* __restrict__ twg4,
    u32* __restrict__ Kfb) {
  __shared__ C2 z[8192];
  const int g = blockIdx.x;
  const int t = threadIdx.x;
  const u16* k0r = KTb + ((size_t)(2 * g) << 12);
  const u16* k1r = KTb + ((size_t)(2 * g + 1) << 12);

  C2 x[16];
#pragma unroll
  for (int k = 0; k < 8; ++k) {
    int l = t + k * 512;
    x[k] = {bf2f(k0r[l]), bf2f(k1r[l])};
  }
#pragma unroll
  for (int k = 8; k < 16; ++k) x[k] = {0.f, 0.f};
#pragma unroll
  for (int r = 0; r < 4; ++r)
    dif4(x[r], x[r + 4], x[r + 8], x[r + 12], twg4[t + r * 512]);
  {
    float4 wv2 = twg4[t << 2];
#pragma unroll
    for (int m = 0; m < 4; ++m)
      dif4(x[4 * m], x[4 * m + 1], x[4 * m + 2], x[4 * m + 3], wv2);
  }
#pragma unroll
  for (int k = 0; k < 16; ++k) z[swz(t + k * 512)] = x[k];
  __syncthreads();

  dif16<7>(z, t, twg4);   __syncthreads();
  dif_pass<3>(z, t, twg4); __syncthreads();
  dif_r8(z, t);            __syncthreads();

  u32* o0 = Kfb + ((size_t)(2 * g) << 13);
  u32* o1 = Kfb + ((size_t)(2 * g + 1) << 13);
#pragma unroll
  for (int it = 0; it < 16; ++it) {
    int p = t + it * 512;
    int k = BR13(p);
    int km = (8192 - k) & 8191;
    int p2 = BR13(km);
    C2 Zk = z[swz(p)], Zm = z[swz(p2)];
    float f0r = 0.5f * (Zk.x + Zm.x), f0i = 0.5f * (Zk.y - Zm.y);
    float f1r = 0.5f * (Zk.y + Zm.y), f1i = 0.5f * (Zm.x - Zk.x);
    o0[p] = (u32)f2bf(f0r) | ((u32)f2bf(f0i) << 16);
    o1[p] = (u32)f2bf(f1r) | ((u32)f2bf(f1i) << 16);
  }
}

// ---------------------------------------------------------------- main FFT conv
__global__ __launch_bounds__(512) void fft_conv4(
    const u16* __restrict__ xdTb, const u32* __restrict__ Kfb,
    const float* __restrict__ meanv, const float* __restrict__ invv,
    const float* __restrict__ n2w, const float* __restrict__ n2b,
    const float* __restrict__ Dv, const float4* __restrict__ twg4,
    u16* __restrict__ dT) {
  __shared__ C2 z[8192];
  const int h = blockIdx.x;
  const int t = threadIdx.x;
  const u16* xr = xdTb + ((size_t)h << 13);
  const float w2h = n2w[h], b2h = n2b[h], Dh = Dv[h];

  float xn0r[8], xn1r[8];
  C2 x[16];
#pragma unroll
  for (int k = 0; k < 8; ++k) {
    int l = t + k * 512;
    float x0 = bf2f(xr[l]);
    float x1 = bf2f(xr[4096 + l]);
    xn0r[k] = (x0 - meanv[l]) * invv[l] * w2h + b2h;
    xn1r[k] = (x1 - meanv[4096 + l]) * invv[4096 + l] * w2h + b2h;
    x[k] = {xn0r[k], xn1r[k]};
  }
#pragma unroll
  for (int k = 8; k < 16; ++k) x[k] = {0.f, 0.f};
#pragma unroll
  for (int r = 0; r < 4; ++r)
    dif4(x[r], x[r + 4], x[r + 8], x[r + 12], twg4[t + r * 512]);
  {
    float4 wv2 = twg4[t << 2];
#pragma unroll
    for (int m = 0; m < 4; ++m)
      dif4(x[4 * m], x[4 * m + 1], x[4 * m + 2], x[4 * m + 3], wv2);
  }
#pragma unroll
  for (int k = 0; k < 16; ++k) z[swz(t + k * 512)] = x[k];
  __syncthreads();

  dif16<7>(z, t, twg4);    __syncthreads();
  dif_pass<3>(z, t, twg4);  __syncthreads();
  r8_fused(z, t, Kfb + ((size_t)h << 13)); __syncthreads();
  dit_pass<3>(z, t, twg4);  __syncthreads();
  dit16<7>(z, t, twg4);     __syncthreads();

#pragma unroll
  for (int k = 0; k < 16; ++k) x[k] = z[swz(t + k * 512)];
  {
    float4 wv2 = twg4[t << 2];
#pragma unroll
    for (int m = 0; m < 4; ++m)
      dit4(x[4 * m], x[4 * m + 1], x[4 * m + 2], x[4 * m + 3], wv2);
  }
  const float sc = 1.0f / 8192.0f;
  u16* drow = dT + ((size_t)h << 13);
#pragma unroll
  for (int r = 0; r < 4; ++r) {
    float4 wv = twg4[t + r * 512];
    C2 w = {wv.x, wv.y}, wm = {wv.y, -wv.x}, wa = {wv.z, wv.w};
    C2 a = x[r], bb = x[r + 4], c = x[r + 8], d = x[r + 12];
    C2 tt = cmul(wa, bb);
    C2 a1 = cadd(a, tt), b1 = csub(a, tt);
    C2 u = cmul(wa, d);
    C2 c1 = cadd(c, u), d1 = csub(c, u);
    C2 olo = cadd(a1, cmul(w, c1));
    C2 ohi = cadd(b1, cmul(wm, d1));
    int l0 = t + r * 512;
    int l1 = t + (r + 4) * 512;
    drow[l0] = f2bf(fmaf(Dh, xn0r[r], olo.x * sc));
    drow[4096 + l0] = f2bf(fmaf(Dh, xn1r[r], -olo.y * sc));
    drow[l1] = f2bf(fmaf(Dh, xn0r[r + 4], ohi.x * sc));
    drow[4096 + l1] = f2bf(fmaf(Dh, xn1r[r + 4], -ohi.y * sc));
  }
}

// ---------------------------------------------------------------- launch
extern "C" void kernel_launch(void* const* d_in, const int* in_sizes, int n_in,
                              void* d_out, int out_size, void* d_ws, size_t ws_size,
                              hipStream_t stream) {
  (void)in_sizes; (void)n_in; (void)out_size; (void)ws_size;
  const float* idx  = (const float*)d_in[0];
  const float* n1w  = (const float*)d_in[1];
  const float* n1b  = (const float*)d_in[2];
  const float* Wxg  = (const float*)d_in[3];
  const float* Wdin = (const float*)d_in[4];
  const float* n2w  = (const float*)d_in[5];
  const float* n2b  = (const float*)d_in[6];
  const float* LR   = (const float*)d_in[7];
  const float* LI   = (const float*)d_in[8];
  const float* CR   = (const float*)d_in[9];
  const float* CI   = (const float*)d_in[10];
  const float* Dv   = (const float*)d_in[11];
  const float* Wgate= (const float*)d_in[12];
  const float* Wout = (const float*)d_in[13];
  const float* bout = (const float*)d_in[14];
  float* out = (float*)d_out;

  const int L = 4096, DIM = 1024, HID = 4096, H = 512;
  const int M = 8192;

  char* p = (char*)d_ws;
  auto alloc = [&](size_t bytes) { char* q = p; p += (bytes + 255) & ~(size_t)255; return q; };
  u16* Wxg_t   = (u16*)alloc((size_t)HID * DIM * 2);
  u16* Wdin_t  = (u16*)alloc((size_t)H * DIM * 2);
  u16* Wgate_t = (u16*)alloc((size_t)HID * H * 2);
  u16* Wout_t  = (u16*)alloc((size_t)DIM * HID * 2);
  u16* xbf     = (u16*)alloc((size_t)M * DIM * 2);    // live until gemm_fuse2
  u16* ebuf    = (u16*)alloc((size_t)M * HID * 2);    // e = gate output
  u16* xdTb    = (u16*)alloc((size_t)H * M * 2);      // bf16 [512][8192]
  float* meanv = (float*)alloc((size_t)M * 4);
  float* invv  = (float*)alloc((size_t)M * 4);
  u16* SRSI    = (u16*)alloc((size_t)L * 1024 * 2);
  u16* Ct      = (u16*)alloc((size_t)H * 1024 * 2);
  u16* KTb     = (u16*)alloc((size_t)H * L * 2);      // bf16 [512][4096]
  u16* dTm     = (u16*)alloc((size_t)H * M * 2);      // d^T [512][8192]
  u16* dbuf    = (u16*)alloc((size_t)M * H * 2);      // d   [8192][512]
  float4* twg4 = (float4*)alloc((size_t)2048 * 16);
  u32* Kfb     = (u32*)alloc((size_t)H * M * 4);      // [512][8192]
  double* aexp = (double*)alloc((size_t)512 * 8);
  double* fexp = (double*)alloc((size_t)512 * 8);

  // 1) mega1: LN1 + 4x weight transpose + twiddle + kgen_c + exp tables
  mega1<<<dim3(8192 + 4096 + 4096 + 2048 + 512 + 1024 + 8 + 2), 256, 0, stream>>>(
      idx, n1w, n1b, Wxg, Wdin, Wgate, Wout,
      Wxg_t, Wdin_t, Wgate_t, Wout_t, xbf, twg4, LR, LI, CR, CI, Ct, aexp, fexp);
  // 2) SRSI (cheap hw-trig version)
  kgen_s2<<<dim3(L * 1024 / 256), 256, 0, stream>>>(aexp, fexp, SRSI);
  // 3) xd^T = Wdin_t @ xbf^T  bf16 [512][8192], grid 256
  gemm128p<1><<<dim3((H / 128) * (M / 128)), 256, 0, stream>>>(
      Wdin_t, xbf, H, M, DIM, nullptr, xdTb, nullptr, nullptr);
  // 4) l3mix: K^T = Ct @ SRSI^T (128 blocks) + LN2 column stats (128 blocks)
  l3mix<<<dim3(256), 256, 0, stream>>>(Ct, SRSI, KTb, xdTb, meanv, invv);
  // 5) Kf spectra (bit-rev bf16), 256 blocks
  kfft2<<<dim3(H / 2), 512, 0, stream>>>(KTb, twg4, Kfb);
  // 6) packed FFT conv -> d^T bf16, 512 blocks
  fft_conv4<<<dim3(H), 512, 0, stream>>>(xdTb, Kfb, meanv, invv, n2w, n2b, Dv, twg4, dTm);
  // 7) d^T -> d
  trans_bf<<<dim3((H / 32) * (M / 32)), 256, 0, stream>>>(dTm, dbuf, H, M);
  // 8) e = (x@Wxg) * (d@Wgate)  — fused two-K-loop GEMM, grid 2048
  gemm_fuse2<<<dim3((M / 128) * (HID / 128)), 256, 0, stream>>>(
      xbf, Wxg_t, DIM, dbuf, Wgate_t, H, M, HID, ebuf);
  // 9) out = e @ Wout + bout + idx (f32), grid 512
  gemm128p<3><<<dim3((M / 128) * (DIM / 128)), 256, 0, stream>>>(
      ebuf, Wout_t, M, DIM, HID, out, nullptr, bout, idx);
}